// Round 3
// baseline (260.663 us; speedup 1.0000x reference)
//
#include <hip/hip_runtime.h>

#define TW 64
#define TH 32
#define SW 72            // staged cols: gx in [tx0-4, tx0+68), 16B-aligned start
#define SH (TH + 6)      // 38 staged rows: gy in [ty0-3, ty0+35)
#define SW4 (SW / 4)     // 18 float4 per staged row
#define SHP 68           // s_h padded row stride (floats): rows shift 4 banks -> conflict-free b128

__device__ __forceinline__ int reflect_idx(int i, int n) {
    // jnp.pad mode="reflect" (border not repeated); halo << n so one fold suffices.
    if (i < 0) i = -i;
    if (i >= n) i = 2 * n - 2 - i;
    return i;
}

__global__ __launch_bounds__(256) void boxblur_kernel(const float* __restrict__ in,
                                                      float* __restrict__ out,
                                                      int H, int W) {
    __shared__ float s_in[SH][SW];    // 38x72 staged patch      (10,944 B)
    __shared__ float s_h[SH][SHP];    // 38x68 horizontal sums   (10,336 B)

    const int tid = threadIdx.x;
    const int img = blockIdx.z;                  // N*C plane
    const int ty0 = blockIdx.y * TH;
    const int tx0 = blockIdx.x * TW;

    const float* __restrict__ src = in + (size_t)img * H * W;
    float* __restrict__ dst = out + (size_t)img * H * W;

    const bool interior_x = (tx0 >= 4) && (tx0 + TW + 4 <= W);

    // ---- stage input patch ----
    if (interior_x) {
        const int gx0 = tx0 - 4;                 // multiple of 4 -> 16B aligned
#pragma unroll
        for (int k = 0; k < 3; ++k) {            // 684 float4 total
            int i = tid + k * 256;
            if (i < SH * SW4) {
                int r = i / SW4;
                int c4 = i - r * SW4;
                int gy = reflect_idx(ty0 - 3 + r, H);
                float4 v = *reinterpret_cast<const float4*>(&src[(size_t)gy * W + gx0 + 4 * c4]);
                *reinterpret_cast<float4*>(&s_in[r][4 * c4]) = v;
            }
        }
    } else {
        // x-edge blocks (2 of 16 per row): scalar staging with x-reflection
        for (int i = tid; i < SH * SW; i += 256) {
            int r = i / SW;
            int c = i - r * SW;
            int gy = reflect_idx(ty0 - 3 + r, H);
            int gx = reflect_idx(tx0 - 4 + c, W);
            s_in[r][c] = src[(size_t)gy * W + gx];
        }
    }
    __syncthreads();

    // ---- horizontal 7-tap sums (3 aligned float4 reads -> 4 outputs) ----
    // output col c taps patch cols c+1 .. c+7
#pragma unroll
    for (int k = 0; k < 3; ++k) {                // 38*16 = 608 float4 total
        int i = tid + k * 256;
        if (i < SH * (TW / 4)) {
            int r = i >> 4;
            int c4 = i & 15;
            float4 v0 = *reinterpret_cast<const float4*>(&s_in[r][4 * c4]);
            float4 v1 = *reinterpret_cast<const float4*>(&s_in[r][4 * c4 + 4]);
            float4 v2 = *reinterpret_cast<const float4*>(&s_in[r][4 * c4 + 8]);
            float a1 = v0.y, a2 = v0.z, a3 = v0.w;
            float a4 = v1.x, a5 = v1.y, a6 = v1.z, a7 = v1.w;
            float a8 = v2.x, a9 = v2.y, a10 = v2.z;
            float o0 = a1 + a2 + a3 + a4 + a5 + a6 + a7;
            float o1 = o0 - a1 + a8;
            float o2 = o1 - a2 + a9;
            float o3 = o2 - a3 + a10;
            *reinterpret_cast<float4*>(&s_h[r][4 * c4]) = make_float4(o0, o1, o2, o3);
        }
    }
    __syncthreads();

    // ---- vertical 7-tap sum + normalize + coalesced float4 store ----
    const float inv = 1.0f / 49.0f;
#pragma unroll
    for (int k = 0; k < 2; ++k) {                // 32*16 = 512 float4 total
        int i = tid + k * 256;
        int r = i >> 4;
        int c4 = i & 15;
        float4 s = *reinterpret_cast<const float4*>(&s_h[r][4 * c4]);
#pragma unroll
        for (int j = 1; j < 7; ++j) {
            float4 v = *reinterpret_cast<const float4*>(&s_h[r + j][4 * c4]);
            s.x += v.x; s.y += v.y; s.z += v.z; s.w += v.w;
        }
        *reinterpret_cast<float4*>(&dst[(size_t)(ty0 + r) * W + tx0 + 4 * c4]) =
            make_float4(s.x * inv, s.y * inv, s.z * inv, s.w * inv);
    }
}

extern "C" void kernel_launch(void* const* d_in, const int* in_sizes, int n_in,
                              void* d_out, int out_size, void* d_ws, size_t ws_size,
                              hipStream_t stream) {
    const float* x = (const float*)d_in[0];
    float* out = (float*)d_out;
    const int H = 1024, W = 1024;
    const int NC = 32 * 3;
    dim3 grid(W / TW, H / TH, NC);   // 16 x 32 x 96
    dim3 block(256);
    boxblur_kernel<<<grid, block, 0, stream>>>(x, out, H, W);
}

// Round 4
// 255.884 us; speedup vs baseline: 1.0187x; 1.0187x over previous
//
#include <hip/hip_runtime.h>

#define TH 64   // output rows per thread

__device__ __forceinline__ int reflect_idx(int i, int n) {
    // jnp.pad mode="reflect" (border not repeated); halo << n so one fold suffices.
    if (i < 0) i = -i;
    if (i >= n) i = 2 * n - 2 - i;
    return i;
}

__device__ __forceinline__ float4 ld4(const float* p) {
    return *reinterpret_cast<const float4*>(p);
}
__device__ __forceinline__ float4 add4(float4 a, float4 b) {
    return make_float4(a.x + b.x, a.y + b.y, a.z + b.z, a.w + b.w);
}
__device__ __forceinline__ float4 sub4(float4 a, float4 b) {
    return make_float4(a.x - b.x, a.y - b.y, a.z - b.z, a.w - b.w);
}

// 4 horizontal 7-tap sums for columns x0..x0+3 of row `row` (W-wide).
template <bool XEDGE>
__device__ __forceinline__ float4 hsum4(const float* __restrict__ row, int x0, int W) {
    float4 B = ld4(row + x0);
    float4 A, C;
    if (XEDGE && x0 == 0)
        A = make_float4(row[4], row[3], row[2], row[1]);        // cols -4..-1 reflected
    else
        A = ld4(row + x0 - 4);
    if (XEDGE && x0 + 4 == W)
        C = make_float4(row[W - 2], row[W - 3], row[W - 4], row[W - 5]); // cols W..W+3 reflected
    else
        C = ld4(row + x0 + 4);
    float h0 = A.y + A.z + A.w + B.x + B.y + B.z + B.w;  // cols x-3..x+3
    float h1 = h0 - A.y + C.x;
    float h2 = h1 - A.z + C.y;
    float h3 = h2 - A.w + C.z;
    return make_float4(h0, h1, h2, h3);
}

template <bool YEDGE>
__device__ __forceinline__ void col_strip(const float* __restrict__ src,
                                          float* __restrict__ dst,
                                          int ty0, int x0, int H, int W) {
    const bool xe = (x0 == 0) || (x0 + 4 == W);
    const float inv = 1.0f / 49.0f;

    float4 w0, w1, w2, w3, w4, w5;
    const float* row;

    // prologue: horizontal sums for rows ty0-3 .. ty0+2
    if (YEDGE) {
#define HROW(k) (src + (size_t)reflect_idx(ty0 - 3 + (k), H) * W)
        w0 = xe ? hsum4<true>(HROW(0), x0, W) : hsum4<false>(HROW(0), x0, W);
        w1 = xe ? hsum4<true>(HROW(1), x0, W) : hsum4<false>(HROW(1), x0, W);
        w2 = xe ? hsum4<true>(HROW(2), x0, W) : hsum4<false>(HROW(2), x0, W);
        w3 = xe ? hsum4<true>(HROW(3), x0, W) : hsum4<false>(HROW(3), x0, W);
        w4 = xe ? hsum4<true>(HROW(4), x0, W) : hsum4<false>(HROW(4), x0, W);
        w5 = xe ? hsum4<true>(HROW(5), x0, W) : hsum4<false>(HROW(5), x0, W);
#undef HROW
    } else {
        row = src + (size_t)(ty0 - 3) * W;
        if (xe) {
            w0 = hsum4<true>(row, x0, W); row += W;
            w1 = hsum4<true>(row, x0, W); row += W;
            w2 = hsum4<true>(row, x0, W); row += W;
            w3 = hsum4<true>(row, x0, W); row += W;
            w4 = hsum4<true>(row, x0, W); row += W;
            w5 = hsum4<true>(row, x0, W); row += W;
        } else {
            w0 = hsum4<false>(row, x0, W); row += W;
            w1 = hsum4<false>(row, x0, W); row += W;
            w2 = hsum4<false>(row, x0, W); row += W;
            w3 = hsum4<false>(row, x0, W); row += W;
            w4 = hsum4<false>(row, x0, W); row += W;
            w5 = hsum4<false>(row, x0, W); row += W;
        }
    }

    float4 vs = add4(add4(add4(w0, w1), add4(w2, w3)), add4(w4, w5));
    float* orow = dst + (size_t)ty0 * W + x0;

#pragma unroll
    for (int r = 0; r < TH; ++r) {
        float4 hn;
        if (YEDGE) {
            const float* rp = src + (size_t)reflect_idx(ty0 + 3 + r, H) * W;
            hn = xe ? hsum4<true>(rp, x0, W) : hsum4<false>(rp, x0, W);
        } else {
            hn = xe ? hsum4<true>(row, x0, W) : hsum4<false>(row, x0, W);
            row += W;
        }
        vs = add4(vs, hn);
        float4 o = make_float4(vs.x * inv, vs.y * inv, vs.z * inv, vs.w * inv);
        *reinterpret_cast<float4*>(orow) = o;
        orow += W;
        vs = sub4(vs, w0);
        w0 = w1; w1 = w2; w2 = w3; w3 = w4; w4 = w5; w5 = hn;
    }
}

__global__ __launch_bounds__(256) void boxblur_kernel(const float* __restrict__ in,
                                                      float* __restrict__ out,
                                                      int H, int W) {
    const int img = blockIdx.z;
    const int ty0 = blockIdx.y * TH;
    const int x0 = threadIdx.x * 4;

    const float* __restrict__ src = in + (size_t)img * H * W;
    float* __restrict__ dst = out + (size_t)img * H * W;

    if (ty0 >= 3 && ty0 + TH + 3 <= H)
        col_strip<false>(src, dst, ty0, x0, H, W);
    else
        col_strip<true>(src, dst, ty0, x0, H, W);
}

extern "C" void kernel_launch(void* const* d_in, const int* in_sizes, int n_in,
                              void* d_out, int out_size, void* d_ws, size_t ws_size,
                              hipStream_t stream) {
    const float* x = (const float*)d_in[0];
    float* out = (float*)d_out;
    const int H = 1024, W = 1024;
    const int NC = 32 * 3;
    dim3 grid(1, H / TH, NC);   // 1 x 16 x 96 = 1536 blocks, 4 waves each
    dim3 block(256);            // thread covers 4 columns: x = 4*tid
    boxblur_kernel<<<grid, block, 0, stream>>>(x, out, H, W);
}

// Round 5
// 247.111 us; speedup vs baseline: 1.0548x; 1.0355x over previous
//
#include <hip/hip_runtime.h>

#define RPT 4            // output rows per thread/block
#define NROWS (RPT + 6)  // 10 input rows touched

__device__ __forceinline__ int reflect_idx(int i, int n) {
    // jnp.pad mode="reflect" (border not repeated); halo << n so one fold suffices.
    if (i < 0) i = -i;
    if (i >= n) i = 2 * n - 2 - i;
    return i;
}

__device__ __forceinline__ float4 ld4(const float* p) {
    return *reinterpret_cast<const float4*>(p);
}

// 4 horizontal 7-tap sums for output cols x0..x0+3 of row `row`.
template <bool XEDGE>
__device__ __forceinline__ float4 hsum4(const float* __restrict__ row, int x0, int W) {
    float4 B = ld4(row + x0);
    float4 A, C;
    if (XEDGE && x0 == 0)
        A = make_float4(row[4], row[3], row[2], row[1]);              // cols -4..-1 reflected
    else
        A = ld4(row + x0 - 4);
    if (XEDGE && x0 + 4 == W)
        C = make_float4(row[W - 2], row[W - 3], row[W - 4], row[W - 5]); // cols W..W+3 reflected
    else
        C = ld4(row + x0 + 4);
    float h0 = A.y + A.z + A.w + B.x + B.y + B.z + B.w;   // cols x-3 .. x+3
    float h1 = h0 - A.y + C.x;
    float h2 = h1 - A.z + C.y;
    float h3 = h2 - A.w + C.z;
    return make_float4(h0, h1, h2, h3);
}

template <bool XE>
__device__ __forceinline__ void body(const float* __restrict__ src,
                                     float* __restrict__ dst,
                                     int rg0, int x0, int H, int W) {
    // 10 row pointers (uniform per block -> scalarized)
    const float* rp[NROWS];
#pragma unroll
    for (int j = 0; j < NROWS; ++j)
        rp[j] = src + (size_t)reflect_idx(rg0 - 3 + j, H) * W;

    // 10 horizontal sums; 30 independent float4 loads, compiler pipelines with counted vmcnt
    float4 w[NROWS];
#pragma unroll
    for (int j = 0; j < NROWS; ++j)
        w[j] = hsum4<XE>(rp[j], x0, W);

    const float inv = 1.0f / 49.0f;
    float4 vs = make_float4(
        w[0].x + w[1].x + w[2].x + w[3].x + w[4].x + w[5].x + w[6].x,
        w[0].y + w[1].y + w[2].y + w[3].y + w[4].y + w[5].y + w[6].y,
        w[0].z + w[1].z + w[2].z + w[3].z + w[4].z + w[5].z + w[6].z,
        w[0].w + w[1].w + w[2].w + w[3].w + w[4].w + w[5].w + w[6].w);

    float* orow = dst + (size_t)rg0 * W + x0;
#pragma unroll
    for (int r = 0; r < RPT; ++r) {
        *reinterpret_cast<float4*>(orow) =
            make_float4(vs.x * inv, vs.y * inv, vs.z * inv, vs.w * inv);
        orow += W;
        if (r < RPT - 1) {
            vs.x += w[r + 7].x - w[r].x;
            vs.y += w[r + 7].y - w[r].y;
            vs.z += w[r + 7].z - w[r].z;
            vs.w += w[r + 7].w - w[r].w;
        }
    }
}

__global__ __launch_bounds__(256) void boxblur_kernel(const float* __restrict__ in,
                                                      float* __restrict__ out,
                                                      int H, int W, int nwg_per_xcd) {
    // bijective XCD-chunked swizzle: adjacent row-groups stay on one XCD's L2
    int bid = blockIdx.x;
    int sbid = (bid & 7) * nwg_per_xcd + (bid >> 3);
    int plane = sbid >> 8;          // 256 row-groups per plane (H/RPT)
    int rg = sbid & 255;
    int rg0 = rg * RPT;

    const float* __restrict__ src = in + (size_t)plane * H * W;
    float* __restrict__ dst = out + (size_t)plane * H * W;

    const int x0 = threadIdx.x * 4;                     // 256 threads cover 1024 cols
    const bool xe = (x0 == 0) || (x0 + 4 == W);

    if (xe) body<true>(src, dst, rg0, x0, H, W);
    else    body<false>(src, dst, rg0, x0, H, W);
}

extern "C" void kernel_launch(void* const* d_in, const int* in_sizes, int n_in,
                              void* d_out, int out_size, void* d_ws, size_t ws_size,
                              hipStream_t stream) {
    const float* x = (const float*)d_in[0];
    float* out = (float*)d_out;
    const int H = 1024, W = 1024;
    const int NC = 32 * 3;
    const int nwg = NC * (H / RPT);     // 96 * 256 = 24576 (divisible by 8)
    dim3 grid(nwg);
    dim3 block(256);
    boxblur_kernel<<<grid, block, 0, stream>>>(x, out, H, W, nwg / 8);
}

// Round 6
// 178.472 us; speedup vs baseline: 1.4605x; 1.3846x over previous
//
#include <hip/hip_runtime.h>

#define TH 64      // output rows per block band
#define ITERS 16   // 4 output rows per iteration

__device__ __forceinline__ int reflect_idx(int i, int n) {
    // jnp.pad mode="reflect" (border not repeated); halo << n so one fold suffices.
    if (i < 0) i = -i;
    if (i >= n) i = 2 * n - 2 - i;
    return i;
}

__device__ __forceinline__ float4 ld4(const float* p) {
    return *reinterpret_cast<const float4*>(p);
}

struct Row3 { float4 A, B, C; };   // cols x0-4..x0-1 | x0..x0+3 | x0+4..x0+7

// Pure loads; x-edge lanes fix up halo by register blend (no extra loads, no divergence).
__device__ __forceinline__ Row3 load_row3(const float* __restrict__ row, int x0, int W,
                                          bool xlo, bool xhi) {
    Row3 r;
    r.B = ld4(row + x0);
    const float* pa = row + (xlo ? x0 : x0 - 4);   // safe dummy addr for edge lane
    const float* pc = row + (xhi ? x0 : x0 + 4);
    r.A = ld4(pa);
    r.C = ld4(pc);
    if (xlo) r.A = make_float4(r.C.x, r.B.w, r.B.z, r.B.y);   // cols {4,3,2,1} reflected
    if (xhi) r.C = make_float4(r.B.z, r.B.y, r.B.x, r.A.w);   // cols {W-2,W-3,W-4,W-5}
    return r;
}

__device__ __forceinline__ float4 hsum(const Row3& t) {
    float h0 = t.A.y + t.A.z + t.A.w + t.B.x + t.B.y + t.B.z + t.B.w;  // cols x-3..x+3
    float h1 = h0 - t.A.y + t.C.x;
    float h2 = h1 - t.A.z + t.C.y;
    float h3 = h2 - t.A.w + t.C.z;
    return make_float4(h0, h1, h2, h3);
}

__global__ __launch_bounds__(256) void boxblur_kernel(const float* __restrict__ in,
                                                      float* __restrict__ out,
                                                      int H, int W, int cpx) {
    // bijective XCD-chunked swizzle: adjacent bands (sharing 6 halo rows) stay on one XCD
    const int bid = blockIdx.x;
    const int sbid = (bid & 7) * cpx + (bid >> 3);
    const int plane = sbid >> 4;            // 16 bands per 1024-row plane
    const int y0 = (sbid & 15) * TH;

    const float* __restrict__ src = in + (size_t)plane * H * W;
    float* __restrict__ dst = out + (size_t)plane * H * W;

    const int x0 = threadIdx.x * 4;         // 256 threads cover 1024 cols
    const bool xlo = (x0 == 0), xhi = (x0 + 4 == W);

    // ---- prologue: hsum window rows y0-3 .. y0+2 ----
    float4 w[10];
#pragma unroll
    for (int j = 0; j < 6; ++j) {
        const float* rp = src + (size_t)reflect_idx(y0 - 3 + j, H) * W;
        w[j] = hsum(load_row3(rp, x0, W, xlo, xhi));
    }
    // ---- prefetch raw rows y0+3 .. y0+6 ----
    Row3 n0 = load_row3(src + (size_t)reflect_idx(y0 + 3, H) * W, x0, W, xlo, xhi);
    Row3 n1 = load_row3(src + (size_t)reflect_idx(y0 + 4, H) * W, x0, W, xlo, xhi);
    Row3 n2 = load_row3(src + (size_t)reflect_idx(y0 + 5, H) * W, x0, W, xlo, xhi);
    Row3 n3 = load_row3(src + (size_t)reflect_idx(y0 + 6, H) * W, x0, W, xlo, xhi);

    const float inv = 1.0f / 49.0f;
    float* orow = dst + (size_t)y0 * W + x0;

#pragma unroll
    for (int t = 0; t < ITERS; ++t) {
        // consume prefetched rows -> hsums
        w[6] = hsum(n0);
        w[7] = hsum(n1);
        w[8] = hsum(n2);
        w[9] = hsum(n3);

        // issue next iteration's 12 loads; they stay in flight through vertical+store
        if (t < ITERS - 1) {
            const int yb = y0 + 4 * t + 7;
            n0 = load_row3(src + (size_t)reflect_idx(yb + 0, H) * W, x0, W, xlo, xhi);
            n1 = load_row3(src + (size_t)reflect_idx(yb + 1, H) * W, x0, W, xlo, xhi);
            n2 = load_row3(src + (size_t)reflect_idx(yb + 2, H) * W, x0, W, xlo, xhi);
            n3 = load_row3(src + (size_t)reflect_idx(yb + 3, H) * W, x0, W, xlo, xhi);
        }

        // vertical sliding sums + 4 coalesced stores
        float4 vs = make_float4(
            w[0].x + w[1].x + w[2].x + w[3].x + w[4].x + w[5].x + w[6].x,
            w[0].y + w[1].y + w[2].y + w[3].y + w[4].y + w[5].y + w[6].y,
            w[0].z + w[1].z + w[2].z + w[3].z + w[4].z + w[5].z + w[6].z,
            w[0].w + w[1].w + w[2].w + w[3].w + w[4].w + w[5].w + w[6].w);
        *reinterpret_cast<float4*>(orow) =
            make_float4(vs.x * inv, vs.y * inv, vs.z * inv, vs.w * inv);
        vs.x += w[7].x - w[0].x; vs.y += w[7].y - w[0].y;
        vs.z += w[7].z - w[0].z; vs.w += w[7].w - w[0].w;
        *reinterpret_cast<float4*>(orow + W) =
            make_float4(vs.x * inv, vs.y * inv, vs.z * inv, vs.w * inv);
        vs.x += w[8].x - w[1].x; vs.y += w[8].y - w[1].y;
        vs.z += w[8].z - w[1].z; vs.w += w[8].w - w[1].w;
        *reinterpret_cast<float4*>(orow + 2 * W) =
            make_float4(vs.x * inv, vs.y * inv, vs.z * inv, vs.w * inv);
        vs.x += w[9].x - w[2].x; vs.y += w[9].y - w[2].y;
        vs.z += w[9].z - w[2].z; vs.w += w[9].w - w[2].w;
        *reinterpret_cast<float4*>(orow + 3 * W) =
            make_float4(vs.x * inv, vs.y * inv, vs.z * inv, vs.w * inv);
        orow += 4 * W;

        // rotate window by 4 (register renames after unroll)
        w[0] = w[4]; w[1] = w[5]; w[2] = w[6];
        w[3] = w[7]; w[4] = w[8]; w[5] = w[9];
    }
}

extern "C" void kernel_launch(void* const* d_in, const int* in_sizes, int n_in,
                              void* d_out, int out_size, void* d_ws, size_t ws_size,
                              hipStream_t stream) {
    const float* x = (const float*)d_in[0];
    float* out = (float*)d_out;
    const int H = 1024, W = 1024;
    const int NC = 32 * 3;
    const int nwg = NC * (H / TH);      // 96 * 16 = 1536 blocks (divisible by 8)
    dim3 grid(nwg);
    dim3 block(256);
    boxblur_kernel<<<grid, block, 0, stream>>>(x, out, H, W, nwg / 8);
}

// Round 8
// 176.178 us; speedup vs baseline: 1.4795x; 1.0130x over previous
//
#include <hip/hip_runtime.h>

#define BH 128   // output rows per band
#define NB 8     // bands per plane (1024/BH)

typedef float f32x4 __attribute__((ext_vector_type(4)));  // native vector for nt-store

__device__ __forceinline__ int reflect_idx(int i, int n) {
    // jnp.pad mode="reflect" (border not repeated); offsets stay < 2n-2.
    if (i < 0) i = -i;
    if (i >= n) i = 2 * n - 2 - i;
    return i;
}

__device__ __forceinline__ float4 ld4(const float* p) {
    return *reinterpret_cast<const float4*>(p);
}

struct Row3 { float4 A, B, C; };   // cols x0-4..x0-1 | x0..x0+3 | x0+4..x0+7

// PURE loads — no consumption of loaded values at issue site (keeps them in flight).
__device__ __forceinline__ Row3 load_row3(const float* __restrict__ row, int x0,
                                          bool xlo, bool xhi) {
    Row3 r;
    r.B = ld4(row + x0);
    const float* pa = row + (xlo ? x0 : x0 - 4);   // safe dummy addr for edge lane
    const float* pc = row + (xhi ? x0 : x0 + 4);
    r.A = ld4(pa);
    r.C = ld4(pc);
    return r;
}

// Deferred x-edge fixup + horizontal 7-tap sums (consume time).
__device__ __forceinline__ float4 hsum_fix(Row3 t, bool xlo, bool xhi) {
    if (xlo) t.A = make_float4(t.C.x, t.B.w, t.B.z, t.B.y);   // cols {4,3,2,1}
    if (xhi) t.C = make_float4(t.B.z, t.B.y, t.B.x, t.A.w);   // cols {W-2..W-5}
    float h0 = t.A.y + t.A.z + t.A.w + t.B.x + t.B.y + t.B.z + t.B.w;  // x-3..x+3
    float h1 = h0 - t.A.y + t.C.x;
    float h2 = h1 - t.A.z + t.C.y;
    float h3 = h2 - t.A.w + t.C.z;
    return make_float4(h0, h1, h2, h3);
}

__global__ __launch_bounds__(256, 3) void boxblur_kernel(const float* __restrict__ in,
                                                         float* __restrict__ out,
                                                         int H, int W, int cpx) {
    // bijective XCD-chunked swizzle: adjacent bands (sharing halo rows) stay on one XCD
    const int bid = blockIdx.x;
    const int sbid = (bid & 7) * cpx + (bid >> 3);
    const int plane = sbid >> 3;            // NB=8 bands per plane
    const int y0 = (sbid & 7) * BH;

    const float* __restrict__ src = in + (size_t)plane * H * W;
    float* __restrict__ dst = out + (size_t)plane * H * W;

    const int x0 = threadIdx.x * 4;         // 256 threads cover 1024 cols
    const bool xlo = (x0 == 0), xhi = (x0 + 4 == W);

    // ---- prologue: h ring slots 1..7 = hsum of input rows y0-4 .. y0+2 ----
    float4 hr[8];
    float4 vs = make_float4(0.f, 0.f, 0.f, 0.f);
#pragma unroll
    for (int j = 0; j < 7; ++j) {
        const float* rp = src + (size_t)reflect_idx(y0 - 4 + j, H) * W;
        float4 h = hsum_fix(load_row3(rp, x0, xlo, xhi), xlo, xhi);
        hr[1 + j] = h;
        vs.x += h.x; vs.y += h.y; vs.z += h.z; vs.w += h.w;
    }

    // ---- fill ring: raw rows y0+3 .. y0+10 into slots 0..7 ----
    Row3 s0 = load_row3(src + (size_t)reflect_idx(y0 + 3, H) * W, x0, xlo, xhi);
    Row3 s1 = load_row3(src + (size_t)reflect_idx(y0 + 4, H) * W, x0, xlo, xhi);
    Row3 s2 = load_row3(src + (size_t)reflect_idx(y0 + 5, H) * W, x0, xlo, xhi);
    Row3 s3 = load_row3(src + (size_t)reflect_idx(y0 + 6, H) * W, x0, xlo, xhi);
    Row3 s4 = load_row3(src + (size_t)reflect_idx(y0 + 7, H) * W, x0, xlo, xhi);
    Row3 s5 = load_row3(src + (size_t)reflect_idx(y0 + 8, H) * W, x0, xlo, xhi);
    Row3 s6 = load_row3(src + (size_t)reflect_idx(y0 + 9, H) * W, x0, xlo, xhi);
    Row3 s7 = load_row3(src + (size_t)reflect_idx(y0 + 10, H) * W, x0, xlo, xhi);

    const float inv = 1.0f / 49.0f;
    float* orow = dst + (size_t)y0 * W + x0;
    int yload = y0 + 11;                    // next input row to fetch (uniform scalar)

    // Phase p (output row r, p = r&7): consume s_p, update running vertical sum,
    // nt-store, then immediately reissue s_p's loads for row r+11 (stays in flight
    // for 8 phases -> 24 loads outstanding, counted vmcnt waits).
#define PHASE(p, pn)                                                              \
    {                                                                             \
        float4 hn = hsum_fix(s##p, xlo, xhi);                                     \
        vs.x += hn.x - hr[pn].x; vs.y += hn.y - hr[pn].y;                         \
        vs.z += hn.z - hr[pn].z; vs.w += hn.w - hr[pn].w;                         \
        hr[p] = hn;                                                               \
        f32x4 o = { vs.x * inv, vs.y * inv, vs.z * inv, vs.w * inv };             \
        __builtin_nontemporal_store(o, reinterpret_cast<f32x4*>(orow));           \
        orow += W;                                                                \
        s##p = load_row3(src + (size_t)reflect_idx(yload, H) * W, x0, xlo, xhi);  \
        ++yload;                                                                  \
    }

    for (int it = 0; it < BH / 8; ++it) {   // 16 macro-iters x 8 rows
        PHASE(0, 1) PHASE(1, 2) PHASE(2, 3) PHASE(3, 4)
        PHASE(4, 5) PHASE(5, 6) PHASE(6, 7) PHASE(7, 0)
    }
#undef PHASE
    // (tail refills load rows up to y0+BH+10, reflected/clamped by reflect_idx —
    //  harmless L1-hit loads whose values are never consumed)
}

extern "C" void kernel_launch(void* const* d_in, const int* in_sizes, int n_in,
                              void* d_out, int out_size, void* d_ws, size_t ws_size,
                              hipStream_t stream) {
    const float* x = (const float*)d_in[0];
    float* out = (float*)d_out;
    const int H = 1024, W = 1024;
    const int NC = 32 * 3;
    const int nwg = NC * NB;            // 96 * 8 = 768 blocks (divisible by 8)
    dim3 grid(nwg);
    dim3 block(256);
    boxblur_kernel<<<grid, block, 0, stream>>>(x, out, H, W, nwg / 8);
}